// Round 22
// baseline (84.035 us; speedup 1.0000x reference)
//
#include <hip/hip_runtime.h>
#include <hip/hip_bf16.h>

typedef __bf16 bf16_t;
typedef __attribute__((ext_vector_type(8))) __bf16 bf16x8;
typedef __attribute__((ext_vector_type(4))) float f32x4;

#define KDIM 1152
#define NDIM 1152
#define BM 128
#define BN 288
#define BK 32
#define NIT 36                        /* K-steps of 32 */
#define NTILES 4                      /* 1152/288 */
#define AB_STEP 8192                  /* BM*BK*2 bytes (bf16 A tile) */
#define B_STEP 18432                  /* BN*BK*2 bytes per ktile */
#define B_TILE (36 * B_STEP)          /* 663552 B per n-tile panel */

__device__ __forceinline__ void gload_lds16(const void* g, void* l) {
    __builtin_amdgcn_global_load_lds(
        (const __attribute__((address_space(1))) void*)g,
        (__attribute__((address_space(3))) void*)l, 16, 0, 0);
}

// W-fold only. Weff: idx(n,k) = tile*331776 + (k>>5)*9216 + (nin>>4)*512
//   + ((k>>3)&3)*128 + (nin&15)*8 + (k&7)   (tile = n/288, nin = n%288)
__global__ void build_wb(const float* __restrict__ W,
                         const float* __restrict__ bvec,
                         bf16_t* __restrict__ Bm,
                         float* __restrict__ bias)
{
    const int t = blockIdx.x * blockDim.x + threadIdx.x;
    if (t < NDIM) {
        const int o = t / 9, p = t - o * 9;
        bias[t] = bvec[p * 128 + o];
    }
    const int c = t & 127;
    const int o = (t >> 7) & 127;
    const int p = t >> 14;
    if (p >= 9) return;
    const int r = p / 3, cc = p - r * 3;
    float eff[3][3] = {{0.f,0.f,0.f},{0.f,0.f,0.f},{0.f,0.f,0.f}};
    const float* w = W + (size_t)((p * 128 + o) * 128 + c) * 9;
    #pragma unroll
    for (int i = 0; i < 3; ++i) {
        const int a = (2 + r + i) / 3;
        #pragma unroll
        for (int j = 0; j < 3; ++j) {
            const int bb = (2 + cc + j) / 3;
            eff[a][bb] += w[i * 3 + j];
        }
    }
    const int n = o * 9 + p;
    const int tile = n / BN;
    const int nin = n - tile * BN;
    #pragma unroll
    for (int a = 0; a < 3; ++a)
        #pragma unroll
        for (int bb = 0; bb < 3; ++bb) {
            const int k = c * 9 + a * 3 + bb;
            const size_t idx = (size_t)tile * (B_TILE / 2)
                             + (k >> 5) * (B_STEP / 2)
                             + (nin >> 4) * 512 + ((k >> 3) & 3) * 128
                             + (nin & 15) * 8 + (k & 7);
            Bm[idx] = (bf16_t)eff[a][bb];
        }
}

// out[16384,1152] = X(fp32) * Weff(bf16) + bias, A converted IN-LOOP.
// Champion skeleton (r17/r19): BM=128 x BN=288, grid 512 = 2 blocks/CU,
// 4 waves (2m x 2n), wave 64x144, acc 4x9.
// A path: per iter each thread loads its 16 fp32 (4 dwordx4 via TWO base
// pointers — 13-bit signed offset limit — rows rg*16+2(u&7),+1 at k-oct
// q=(u>>3)&3), cvts to 2 bf16x8, ds_writes 32B into Af[nxt] in
// frag-contiguous order [rg(8)][q(4)][ri(16)] (proven Xb layout; reads
// contiguous-1KB, 0 conflicts).
// Ledger (in-order VMEM): enter [B(t+1)5, A(t+2)4]; GLDB(t+2)+5;
// WAITV(5) (A(t+2) ready, B(t+1) drained); CVTW->Af[cur]; LOADA(t+3)+4;
// MFMA36; BAR. vmcnt 0 only at the tail.
__launch_bounds__(256, 2)
__global__ void ind_gemm(const float* __restrict__ X,
                         const bf16_t* __restrict__ Bm,
                         const float* __restrict__ bias,
                         float* __restrict__ out)
{
    __shared__ char Af[2][AB_STEP];
    __shared__ char Bs[2][B_STEP];
    __shared__ char Scrap[1024];

    const int tid = threadIdx.x;
    const int lane = tid & 63;
    const int wid = tid >> 6;
    const int wm = wid >> 1;        // 0..1
    const int wn = wid & 1;         // 0..1

    // XCD swizzle: 512 blocks = 64/XCD; consecutive swz share an m-panel
    // (X panel 590KB fp32, L2-resident) across the 4 n-tiles.
    const int bid = blockIdx.x;
    const int swz = (bid & 7) * 64 + (bid >> 3);
    const int mt = swz >> 2;
    const int nt = swz & 3;
    const int m0 = mt * BM;

    // A reg-load addressing: thread u -> rg=u>>5, q=(u>>3)&3, rows rg*16+2(u&7),+1
    const int arow = (tid >> 5) * 16 + 2 * (tid & 7);
    const char* a_src  = (const char*)(X + (size_t)(m0 + arow) * KDIM
                                         + ((tid >> 3) & 3) * 8);
    const char* a_src2 = a_src + (size_t)KDIM * 4;   // row+1 (4608 B away)
    const int fr = (lane >> 4) * 256 + (lane & 15) * 16;
    const char* bpanel = (const char*)Bm + (size_t)nt * B_TILE;

    f32x4 acc[4][9];
    #pragma unroll
    for (int i = 0; i < 4; ++i)
        #pragma unroll
        for (int j = 0; j < 9; ++j)
            acc[i][j] = (f32x4){0.f, 0.f, 0.f, 0.f};

    f32x4 ra[4];                    // in-flight A fp32 (single set, WAR-reused)
    bf16x8 af[4], bfr[9];

    // issue order ra[0],ra[1],ra[2],ra[3] — ledger counts on it
    #define LOADA(T) do {                                                   \
        const char* p0_ = a_src  + (size_t)(T) * 128;                       \
        const char* p1_ = a_src2 + (size_t)(T) * 128;                       \
        asm volatile("global_load_dwordx4 %0, %2, off\n\t"                  \
                     "global_load_dwordx4 %1, %2, off offset:16"            \
                     : "=&v"(ra[0]), "=&v"(ra[1])                           \
                     : "v"(p0_) : "memory");                                \
        asm volatile("global_load_dwordx4 %0, %2, off\n\t"                  \
                     "global_load_dwordx4 %1, %2, off offset:16"            \
                     : "=&v"(ra[2]), "=&v"(ra[3])                           \
                     : "v"(p1_) : "memory");                                \
    } while (0)

    #define CVTW(BUF) do {                                                  \
        bf16x8 w0_, w1_;                                                    \
        _Pragma("unroll")                                                   \
        for (int e_ = 0; e_ < 4; ++e_) {                                    \
            w0_[e_]     = (__bf16)ra[0][e_];                                \
            w0_[4 + e_] = (__bf16)ra[1][e_];                                \
            w1_[e_]     = (__bf16)ra[2][e_];                                \
            w1_[4 + e_] = (__bf16)ra[3][e_];                                \
        }                                                                   \
        *(bf16x8*)(&Af[BUF][tid * 32])      = w0_;                          \
        *(bf16x8*)(&Af[BUF][tid * 32 + 16]) = w1_;                          \
    } while (0)

    #define GLDB(T, BUF) do {                                               \
        const char* sb_ = bpanel + (size_t)(T) * B_STEP;                    \
        _Pragma("unroll")                                                   \
        for (int r_ = 0; r_ < 4; ++r_) {                                    \
            const int u_ = (tid + r_ * 256) * 16;                           \
            gload_lds16(sb_ + u_, &Bs[BUF][u_]);                            \
        }                                                                   \
        if (tid < 128) gload_lds16(sb_ + (1024 + tid) * 16,                 \
                                   &Bs[BUF][(1024 + tid) * 16]);            \
        else           gload_lds16(bpanel + tid * 16, Scrap);               \
    } while (0)

    #define RD(CUR) do {                                                    \
        _Pragma("unroll")                                                   \
        for (int mi_ = 0; mi_ < 4; ++mi_)                                   \
            af[mi_] = *(const bf16x8*)(&Af[CUR][(wm * 4 + mi_) * 1024 + fr]); \
        _Pragma("unroll")                                                   \
        for (int j_ = 0; j_ < 9; ++j_)                                      \
            bfr[j_] = *(const bf16x8*)(&Bs[CUR][(wn * 9 + j_) * 1024 + fr]); \
        asm volatile("s_waitcnt lgkmcnt(0)" ::: "memory");                  \
        __builtin_amdgcn_sched_barrier(0);                                  \
        __builtin_amdgcn_s_barrier();                                       \
    } while (0)

    #define MFMA36() do {                                                   \
        __builtin_amdgcn_s_setprio(1);                                      \
        _Pragma("unroll")                                                   \
        for (int mi_ = 0; mi_ < 4; ++mi_)                                   \
            _Pragma("unroll")                                               \
            for (int j_ = 0; j_ < 9; ++j_)                                  \
                acc[mi_][j_] = __builtin_amdgcn_mfma_f32_16x16x32_bf16(     \
                    af[mi_], bfr[j_], acc[mi_][j_], 0, 0, 0);               \
        __builtin_amdgcn_s_setprio(0);                                      \
    } while (0)

    #define WAITV(N) do {                                                   \
        asm volatile("s_waitcnt vmcnt(" #N ")" ::: "memory");               \
        __builtin_amdgcn_sched_barrier(0);                                  \
    } while (0)

    // ---- prologue: build Af[0]=A(0), Af[1]=A(1); B(0),B(1); A(2) in regs ----
    LOADA(0);
    WAITV(0);
    CVTW(0);
    LOADA(1);                        // [A1:4]
    GLDB(0, 0);                      // [A1:4, B0:5]
    GLDB(1, 1);                      // [A1:4, B0:5, B1:5] = 14
    WAITV(10);                       // A(1) done (in-order); B0,B1 fly
    CVTW(1);
    LOADA(2);                        // [B0:5, B1:5, A2:4] = 14
    WAITV(9);                        // drain B(0); leaves [B1:5, A2:4] = 9
    asm volatile("s_waitcnt lgkmcnt(0)" ::: "memory");
    __builtin_amdgcn_sched_barrier(0);
    __builtin_amdgcn_s_barrier();

    // steady state: t = 0..31 (16 double-iters), invariant entry [B(t+1)5, A(t+2)4]
    #pragma unroll 1
    for (int t2 = 0; t2 < 16; ++t2) {
        const int t = 2 * t2;
        // ---- even iter t (cur=0) ----
        RD(0);                       // 13 ds_read + lgkm0 + barrier (frees buf0)
        GLDB(t + 2, 0);              // -> [B(t+1)5, A(t+2)4, B(t+2)5]
        WAITV(5);                    // A(t+2) ready; B(t+1) drained
        CVTW(0);                     // A(t+2) -> Af[0]
        LOADA(t + 3);                // -> [B(t+2)5, A(t+3)4]
        MFMA36();
        __builtin_amdgcn_s_barrier();
        // ---- odd iter t+1 (cur=1) ----
        RD(1);
        GLDB(t + 3, 1);
        WAITV(5);
        CVTW(1);
        LOADA(t + 4);
        MFMA36();
        __builtin_amdgcn_s_barrier();
    }
    // ---- t = 32 (cur=0): full ----
    RD(0);
    GLDB(34, 0);
    WAITV(5);
    CVTW(0);                         // A(34) -> Af[0]
    LOADA(35);
    MFMA36();
    __builtin_amdgcn_s_barrier();
    // ---- t = 33 (cur=1): last stage, no LOADA ----
    RD(1);
    GLDB(35, 1);
    WAITV(5);                        // A(35) ready; B(34) drained
    CVTW(1);                         // A(35) -> Af[1]
    MFMA36();
    __builtin_amdgcn_s_barrier();    // outstanding: [B(35)5]
    // ---- t = 34 (cur=0): drain all ----
    RD(0);
    WAITV(0);
    MFMA36();
    __builtin_amdgcn_s_barrier();
    // ---- t = 35 (cur=1): compute-only ----
    RD(1);
    MFMA36();

    #undef LOADA
    #undef CVTW
    #undef GLDB
    #undef RD
    #undef MFMA36
    #undef WAITV

    // ---- epilogue: C/D col=lane&15, row=(lane>>4)*4+reg ----
    const int orow = (lane >> 4) * 4;
    const int ocol = lane & 15;
    const int gn0 = nt * BN + wn * 144 + ocol;
    #pragma unroll
    for (int ni = 0; ni < 9; ++ni) {
        const float bv = bias[gn0 + ni * 16];
        #pragma unroll
        for (int mi = 0; mi < 4; ++mi) {
            float* po = out + (size_t)(m0 + wm * 64 + mi * 16 + orow) * NDIM
                            + gn0 + ni * 16;
            #pragma unroll
            for (int r = 0; r < 4; ++r)
                po[(size_t)r * NDIM] = acc[mi][ni][r] + bv;
        }
    }
}

extern "C" void kernel_launch(void* const* d_in, const int* in_sizes, int n_in,
                              void* d_out, int out_size, void* d_ws, size_t ws_size,
                              hipStream_t stream)
{
    const float* x  = (const float*)d_in[0];
    const float* W  = (const float*)d_in[1];
    const float* bv = (const float*)d_in[2];
    float* out = (float*)d_out;

    // ws: Bm 2.65 MB | bias 4.6 KB
    bf16_t* Bm   = (bf16_t*)d_ws;
    float*  bias = (float*)((char*)d_ws + (size_t)KDIM * NDIM * sizeof(bf16_t));

    build_wb<<<576, 256, 0, stream>>>(W, bv, Bm, bias);
    ind_gemm<<<512, 256, 0, stream>>>(x, Bm, bias, out);
}